// Round 16
// baseline (220.662 us; speedup 1.0000x reference)
//
#include <hip/hip_runtime.h>
#include <hip/hip_bf16.h>
#include <cstdint>
#include <cstddef>

// Problem constants (fixed shapes per reference)
#define NROWS 8192
#define DIM   1024
#define BMR 128           // block rows (2 waves x 64)
#define BNC 128           // block cols
#define BK  64            // K depth per iteration; 16 iterations
#define NBLK 2080         // 64*65/2 triangle tiles = 8 XCDs x 260
#define EPS 1e-8f
// E pre-scaled by sqrt(10*log2(e)) so MFMA accumulates 10*log2(e)*<a,b>;
// epilogue is a bare exp2f.
#define PRESCALE 3.798288f

typedef short  bf16x8   __attribute__((ext_vector_type(8)));
typedef float  floatx16 __attribute__((ext_vector_type(16)));

typedef __attribute__((address_space(1))) const void CGV;
typedef __attribute__((address_space(3))) void LV;

__device__ __forceinline__ void async_load16(const void* g, void* l) {
    __builtin_amdgcn_global_load_lds((CGV*)g, (LV*)l, 16, 0, 0);
}

__device__ __forceinline__ unsigned short f2bf_rne(float f) {
    union { float f; unsigned u; } c; c.f = f;
    unsigned u = c.u;
    unsigned r = (u + 0x7fffu + ((u >> 16) & 1u)) >> 16;
    return (unsigned short)r;
}

// ---------------------------------------------------------------------------
// Kernel A: fp32 -> bf16 (RNE) with PRESCALE folded in. First 64 blocks also
// zero the 16384-float accumulator region.
// ---------------------------------------------------------------------------
__global__ __launch_bounds__(256) void convert_kernel(
    const float* __restrict__ in, unsigned short* __restrict__ out,
    float* __restrict__ accum /* all_sum ++ pos_sum, 2*NROWS floats */)
{
    int i = (blockIdx.x * 256 + threadIdx.x) * 4;
    float4 v = *(const float4*)(in + i);
    ushort4 o;
    o.x = f2bf_rne(v.x * PRESCALE);
    o.y = f2bf_rne(v.y * PRESCALE);
    o.z = f2bf_rne(v.z * PRESCALE);
    o.w = f2bf_rne(v.w * PRESCALE);
    *(ushort4*)(out + i) = o;
    if (blockIdx.x < (2 * NROWS) / 256)
        accum[blockIdx.x * 256 + threadIdx.x] = 0.0f;
}

// ---------------------------------------------------------------------------
// Kernel B: symmetric-half fused GEMM — R12 structure (110 us, best measured)
// with the MFMA shape switched to 32x32x16 (m119: 2495 TF vs 2075 — 20%
// faster per FLOP, half the MFMA instruction count; LDS bytes unchanged).
// Wave tile 64x128 = 2x4 grid of 32x32 tiles; per wave-iter 4 K-steps of 16:
// 6 ds_read_b128 -> 8 MFMAs each (24 reads / 32 MFMAs total).
// A/B fragment: m=lane&31, k=(lane>>5)*8+j -> one 16B chunk (2s+half) of the
// row's 8-chunk K-slice, at swizzled slot ^(row&7)=^(lane&7) (same aggregate
// slot pattern as the measured-0-conflict 16x16 scheme).
// C/D layout (HW-verified m74/m101): col=lane&31,
// row=(reg&3)+8*(reg>>2)+4*(lane>>5).
// Everything else verbatim R12: 2-wave blocks (4 barrier domains/CU),
// global_load_lds w16 staging + 2 __syncthreads, chunk swizzle c^(row&7),
// UNIFORM strictly-lower symmetry, XCD-local tile order.
// ---------------------------------------------------------------------------
__global__ __launch_bounds__(128, 2) void gemm_fused_kernel(
    const unsigned short* __restrict__ E,   // bf16 bits (prescaled), [NROWS][DIM]
    const int*            __restrict__ labels,
    float*                __restrict__ all_sum,
    float*                __restrict__ pos_sum)
{
    __shared__ __align__(16) unsigned short sA[BMR * BK];   // 16 KB
    __shared__ __align__(16) unsigned short sB[BNC * BK];   // 16 KB

    const int tid  = threadIdx.x;
    const int lane = tid & 63;
    const int w    = tid >> 6;      // wave 0/1 -> rows w*64..w*64+63 of block
    const int l31  = lane & 31;
    const int half = lane >> 5;

    // XCD-local linear tile id, then sqrt triangle decode (strips of 128).
    const int b = blockIdx.x;
    const int t = (b & 7) * 260 + (b >> 3);     // 2080 = 8 x 260
    int bi = (int)((sqrtf(8.0f * (float)t + 1.0f) - 1.0f) * 0.5f);
    while ((bi + 1) * (bi + 2) / 2 <= t) ++bi;
    while (bi * (bi + 1) / 2 > t) --bi;
    const int bj = t - bi * (bi + 1) / 2;

    const int rBase = bi * BMR;     // rows (A tile)
    const int cBase = bj * BNC;     // cols (B tile)

    // Staging (verbatim R12): tile = 128x64 elems = 1024 chunks of 16B;
    // 128 threads x 8 passes (rows srow + 16j). Slot (t&7) of row srow holds
    // global chunk (t&7) ^ (srow&7); srow&7 invariant under +16.
    const int srow = tid >> 3;                          // 0..15
    const int scol = (((tid & 7) ^ (srow & 7)) << 3);   // elem col 0..56
    const int e0   = tid * 8;                           // LDS elem offset/pass

    floatx16 acc[2][4];
    #pragma unroll
    for (int i = 0; i < 2; ++i)
        #pragma unroll
        for (int j = 0; j < 4; ++j)
            acc[i][j] = (floatx16)0.0f;

    // Fragment reads: A row = w*64 + mt*32 + l31; B row = nt*32 + l31.
    // K-step s (16 wide): lane needs chunk 2s+half, at slot ^(row&7)=^(lane&7).
    const int swz = lane & 7;
    int aRow0[2], bRow0[4];
    #pragma unroll
    for (int mt = 0; mt < 2; ++mt) aRow0[mt] = (w * 64 + mt * 32 + l31) * BK;
    #pragma unroll
    for (int nt = 0; nt < 4; ++nt) bRow0[nt] = (nt * 32 + l31) * BK;

    const size_t gA0 = (size_t)(rBase + srow) * DIM + scol;
    const size_t gB0 = (size_t)(cBase + srow) * DIM + scol;
    const size_t rstep = (size_t)16 * DIM;

    for (int k0 = 0; k0 < DIM; k0 += BK) {
        __syncthreads();   // previous compute done before overwrite
        #pragma unroll
        for (int j = 0; j < 8; ++j)
            async_load16(E + gA0 + j * rstep + k0, &sA[e0 + j * 1024]);
        #pragma unroll
        for (int j = 0; j < 8; ++j)
            async_load16(E + gB0 + j * rstep + k0, &sB[e0 + j * 1024]);
        __syncthreads();   // vmcnt drained by compiler before barrier

        #pragma unroll
        for (int s = 0; s < 4; ++s) {
            const int cOff = ((((s << 1) | half) ^ swz) << 3);
            bf16x8 aF[2], bF[4];
            #pragma unroll
            for (int mt = 0; mt < 2; ++mt)
                aF[mt] = *(const bf16x8*)&sA[aRow0[mt] + cOff];
            #pragma unroll
            for (int nt = 0; nt < 4; ++nt)
                bF[nt] = *(const bf16x8*)&sB[bRow0[nt] + cOff];

            #pragma unroll
            for (int mt = 0; mt < 2; ++mt)
                #pragma unroll
                for (int nt = 0; nt < 4; ++nt)
                    acc[mt][nt] = __builtin_amdgcn_mfma_f32_32x32x16_bf16(
                        aF[mt], bF[nt], acc[mt][nt], 0, 0, 0);
        }
    }

    // Epilogue. C/D layout (32x32, HW-verified m74/m101): col = lane&31,
    // row = (reg&3) + 8*(reg>>2) + 4*half.
    // Uniform rule (R11/R12-verified): element (grow, gcol) counts iff
    // grow > gcol; contributes to row grow AND col gcol.
    float labc[4];
    int   gcol[4];
    #pragma unroll
    for (int nt = 0; nt < 4; ++nt) {
        gcol[nt] = cBase + nt * 32 + l31;
        labc[nt] = (float)labels[gcol[nt]];
    }

    float colAll[4] = {0.f, 0.f, 0.f, 0.f};
    float colPos[4] = {0.f, 0.f, 0.f, 0.f};

    #pragma unroll
    for (int mt = 0; mt < 2; ++mt) {
        #pragma unroll
        for (int r = 0; r < 16; ++r) {
            const int rl   = (r & 3) + 8 * (r >> 2) + 4 * half;
            const int grow = rBase + w * 64 + mt * 32 + rl;
            const float labr = (float)labels[grow];
            float sAll = 0.f, sPos = 0.f;
            #pragma unroll
            for (int nt = 0; nt < 4; ++nt) {
                float ev = exp2f(acc[mt][nt][r]);   // PRESCALE folded into E
                ev = (grow > gcol[nt]) ? ev : 0.0f; // strictly-lower only
                sAll += ev;
                sPos += ev * labc[nt];
                colAll[nt] += ev;
                colPos[nt] += ev * labr;
            }
            // row-reduce across the 32 lanes (same half) sharing this row
            #pragma unroll
            for (int off = 1; off < 32; off <<= 1) {
                sAll += __shfl_xor(sAll, off);
                sPos += __shfl_xor(sPos, off);
            }
            if (l31 == 0 && sAll != 0.f) {
                atomicAdd(&all_sum[grow], sAll);
                atomicAdd(&pos_sum[grow], sPos);
            }
        }
    }

    // col-reduce: combine the two halves (lanes differing in bit 5)
    #pragma unroll
    for (int nt = 0; nt < 4; ++nt) {
        float a = colAll[nt], p = colPos[nt];
        a += __shfl_xor(a, 32);  p += __shfl_xor(p, 32);
        if (half == 0 && a != 0.f) {
            atomicAdd(&all_sum[gcol[nt]], a);
            atomicAdd(&pos_sum[gcol[nt]], p);
        }
    }
}

// ---------------------------------------------------------------------------
// Kernel C: loss = mean over rows with lab==1 of -log(pos/(all+eps)); 0 if n_ref<2
// ---------------------------------------------------------------------------
__global__ __launch_bounds__(1024) void finalize_kernel(
    const float* __restrict__ all_sum,
    const float* __restrict__ pos_sum,
    const int*   __restrict__ labels,
    float*       __restrict__ out)
{
    __shared__ float sSum[1024];
    __shared__ float sCnt[1024];
    const int tid = threadIdx.x;
    float lsum = 0.f, lcnt = 0.f;
    for (int i = tid; i < NROWS; i += 1024) {
        if (labels[i] > 0) {
            float p = pos_sum[i];
            float a = all_sum[i] + EPS;
            lsum += -logf(p / a);
            lcnt += 1.0f;
        }
    }
    sSum[tid] = lsum;
    sCnt[tid] = lcnt;
    __syncthreads();
    for (int s = 512; s > 0; s >>= 1) {
        if (tid < s) { sSum[tid] += sSum[tid + s]; sCnt[tid] += sCnt[tid + s]; }
        __syncthreads();
    }
    if (tid == 0) {
        float n = sCnt[0];
        out[0] = (n < 2.0f) ? 0.0f : sSum[0] / fmaxf(n, 1.0f);
    }
}

// ---------------------------------------------------------------------------
extern "C" void kernel_launch(void* const* d_in, const int* in_sizes, int n_in,
                              void* d_out, int out_size, void* d_ws, size_t ws_size,
                              hipStream_t stream) {
    const float* emb    = (const float*)d_in[0];
    const int*   labels = (const int*)d_in[1];
    float*       out    = (float*)d_out;

    // workspace layout: [bf16 E: 16 MB][all_sum: 32 KB][pos_sum: 32 KB]
    unsigned short* Ebf = (unsigned short*)d_ws;
    const size_t embBytes = (size_t)NROWS * DIM * sizeof(unsigned short);
    float* all_sum = (float*)((char*)d_ws + embBytes);
    float* pos_sum = all_sum + NROWS;

    convert_kernel<<<(NROWS * DIM) / (4 * 256), 256, 0, stream>>>(emb, Ebf, all_sum);

    gemm_fused_kernel<<<NBLK, 128, 0, stream>>>(Ebf, labels, all_sum, pos_sum);

    finalize_kernel<<<1, 1024, 0, stream>>>(all_sum, pos_sum, labels, out);
}